// Round 5
// baseline (49.556 us; speedup 1.0000x reference)
//
#include <hip/hip_runtime.h>
#include <cstddef>

static constexpr int B = 64, T = 64, V = 64, C = 65;
static constexpr int NB = 4;                       // gather blocks per batch
static constexpr float NEG   = -1.0e30f;           // log-space "zero"
static constexpr float LOG2E = 1.44269504088896340736f;
static constexpr float LN2   = 0.69314718055994530942f;

// Raw HW transcendentals: v_exp_f32 = 2^x, v_log_f32 = log2(x).
__device__ __forceinline__ float fexp2(float x) {
    float r; asm("v_exp_f32 %0, %1" : "=v"(r) : "v"(x)); return r;
}
__device__ __forceinline__ float flog2(float x) {
    float r; asm("v_log_f32 %0, %1" : "=v"(r) : "v"(x)); return r;
}
// lane i <- lane i-1; lane 0 <- NEG sentinel (folded into the DPP `old`).
__device__ __forceinline__ float shr1(float x, int negi) {
    return __int_as_float(__builtin_amdgcn_update_dpp(
        negi, __float_as_int(x), 0x138 /*wave_shr:1*/, 0xf, 0xf, false));
}

// ---- DP pieces (shared by fused + fallback kernels) ----

__device__ __forceinline__ void dp_stage(const float* __restrict__ gsrc,
                                         float* __restrict__ sc, int tid) {
    const float4* __restrict__ src = (const float4*)gsrc;
    float4* dst = (float4*)sc;
    #pragma unroll
    for (int j = 0; j < 12; ++j) dst[tid + j * 256] = src[tid + j * 256];
}

// 126-step anti-diagonal chain, one wave, log2-domain, depth-7 LDS prefetch.
// Alpha stored diagonal-major; inactive lanes' garbage lands in never-read slots.
__device__ __forceinline__ void dp_chain(const float* __restrict__ sc,
                                         float* __restrict__ sAd, int v) {
    const int negi = __float_as_int(NEG);
    float a1 = (v == 0) ? 0.0f : NEG;
    float a2 = NEG;
    constexpr int PD = 7;                           // 126 = 17*7 + 7
    float pD[PD], pI[PD], pS[PD];
    #pragma unroll
    for (int k = 0; k < PD; ++k) {
        const int tc = min(max(1 + k - v, 0), T - 1);
        const int off = tc * V + v;
        pD[k] = sc[off]; pI[k] = sc[T*V + off]; pS[k] = sc[2*T*V + off];
    }
    for (int gq = 0; gq < 17; ++gq) {
        #pragma unroll
        for (int k = 0; k < PD; ++k) {
            const int d = gq * PD + 1 + k;
            const float lf1 = shr1(a1, negi);       // alpha[t,   v-1]
            const float lf2 = shr1(a2, negi);       // alpha[t-1, v-1]
            const float xd = pD[k] + a1;
            const float xs = pS[k] + lf2;
            const float xi = pI[k] + lf1;
            {   // prefetch step d+PD (needed ~350 cy later)
                const int tc = min(max(d + PD - v, 0), T - 1);
                const int off = tc * V + v;
                pD[k] = sc[off]; pI[k] = sc[T*V + off]; pS[k] = sc[2*T*V + off];
            }
            const float m = fmaxf(fmaxf(xd, xs), xi);           // v_max3_f32
            const float s = fexp2(xd - m) + fexp2(xs - m) + fexp2(xi - m);
            const float a = m + flog2(s);
            sAd[d * V + v] = a;                     // unconditional, off-chain
            a2 = a1; a1 = a;
        }
    }
    #pragma unroll
    for (int k = 0; k < PD; ++k) {                  // epilogue d = 120..126
        const int d = 120 + k;
        const float lf1 = shr1(a1, negi);
        const float lf2 = shr1(a2, negi);
        const float xd = pD[k] + a1;
        const float xs = pS[k] + lf2;
        const float xi = pI[k] + lf1;
        const float m = fmaxf(fmaxf(xd, xs), xi);
        const float s = fexp2(xd - m) + fexp2(xs - m) + fexp2(xi - m);
        const float a = m + flog2(s);
        sAd[d * V + v] = a;
        a2 = a1; a1 = a;
    }
}

__device__ __forceinline__ void dp_writeout(const float* __restrict__ sAd,
                                            float* __restrict__ out, int b, int tid) {
    #pragma unroll
    for (int j = 0; j < 4; ++j) {
        const int idx = tid + j * 256;              // f4 tile 0..1023
        const int t = idx >> 4, v4 = (idx & 15) * 4;
        float4 r;
        r.x = sAd[(t + v4 + 0) * V + v4 + 0] * LN2;
        r.y = sAd[(t + v4 + 1) * V + v4 + 1] * LN2;
        r.z = sAd[(t + v4 + 2) * V + v4 + 2] * LN2;
        r.w = sAd[(t + v4 + 3) * V + v4 + 3] * LN2;
        ((float4*)out)[(size_t)b * 1024 + idx] = r;
    }
}

// ---- Fused persistent producer/consumer kernel ----
// 256 blocks (4/batch) x 256 threads, 80 KB LDS -> 2 blocks/CU capacity ->
// all blocks co-resident: the 64 spinners can never starve the producers.
__global__ void __launch_bounds__(256) fused_kernel(
    const float* __restrict__ as,
    const int* __restrict__ del_ids,    // [B,T]
    const int* __restrict__ ins_ids,    // [B,V]
    const int* __restrict__ sub_ids,    // [B,T,V]
    float* __restrict__ g,              // [B][3][T*V]  (ws)
    int* __restrict__ flags,            // [B]          (ws, memset to 0)
    float* __restrict__ out)
{
    __shared__ __align__(16) float sc[3 * T * V];   // 48 KB
    __shared__ __align__(16) float sAd[128 * V];    // 32 KB, diag-major alpha
    const int b = blockIdx.x >> 2, j = blockIdx.x & (NB - 1);
    const int tid = threadIdx.x;

    // Phase 1: gather quarter j of batch b (12 scattered picks / thread).
    // p is kind-major: [3][T][V] flat; kind is wave-uniform (64-aligned chunks).
    {
        const int base = j * 3072;
        #pragma unroll
        for (int k = 0; k < 12; ++k) {
            const int p = base + k * 256 + tid;
            const int kind = p >> 12, rem = p & 4095;
            const int t = rem >> 6, v = rem & 63;
            int id;
            if (kind == 0)      id = del_ids[b * T + t];     // scalar
            else if (kind == 1) id = ins_ids[b * V + v];
            else                id = sub_ids[(b * T + t) * V + v];
            g[b * 12288 + p] = as[(size_t)((b * T + t) * V + v) * C + id] * LOG2E;
        }
    }
    __syncthreads();
    if (tid == 0) {
        __threadfence();                            // release: flush writes
        atomicAdd(flags + b, 1);                    // device-scope by default
    }
    if (j != 0) return;

    // Phase 2 (one block per batch): wait for all 4 quarters, then DP.
    if (tid == 0) {
        // MUST be an agent-scope atomic load: plain/volatile loads can hit a
        // stale per-XCD L2 line forever (atomics resolve past L2).
        while (__hip_atomic_load(flags + b, __ATOMIC_RELAXED,
                                 __HIP_MEMORY_SCOPE_AGENT) < NB)
            __builtin_amdgcn_s_sleep(4);
        __threadfence();                            // acquire: invalidate caches
    }
    __syncthreads();
    dp_stage(g + b * 12288, sc, tid);
    if (tid == 0) sAd[0] = 0.0f;                    // alpha[0][0]
    __syncthreads();
    if (tid < 64) dp_chain(sc, sAd, tid);
    __syncthreads();
    dp_writeout(sAd, out, b, tid);
}

// ---- Fallback: two-kernel path (round-4 structure) ----

__global__ void __launch_bounds__(192) gather_kernel(
    const float* __restrict__ as, const int* __restrict__ del_ids,
    const int* __restrict__ ins_ids, const int* __restrict__ sub_ids,
    float* __restrict__ g)
{
    const int bt = blockIdx.x, b = bt >> 6, t = bt & 63;
    const int tid = threadIdx.x, v = tid & 63, kind = tid >> 6;
    int id;
    if (kind == 0)      id = del_ids[bt];
    else if (kind == 1) id = ins_ids[b * V + v];
    else                id = sub_ids[bt * V + v];
    g[((b * 3 + kind) * T + t) * V + v] =
        as[(size_t)(bt * V + v) * C + id] * LOG2E;
}

__global__ void __launch_bounds__(256) dp_kernel(
    const float* __restrict__ g, float* __restrict__ out)
{
    __shared__ __align__(16) float sc[3 * T * V];
    __shared__ __align__(16) float sAd[128 * V];
    const int b = blockIdx.x, tid = threadIdx.x;
    dp_stage(g + (size_t)b * 12288, sc, tid);
    if (tid == 0) sAd[0] = 0.0f;
    __syncthreads();
    if (tid < 64) dp_chain(sc, sAd, tid);
    __syncthreads();
    dp_writeout(sAd, out, b, tid);
}

extern "C" void kernel_launch(void* const* d_in, const int* in_sizes, int n_in,
                              void* d_out, int out_size, void* d_ws, size_t ws_size,
                              hipStream_t stream) {
    const float* as      = (const float*)d_in[0];
    const int*   del_ids = (const int*)d_in[1];
    const int*   ins_ids = (const int*)d_in[2];
    const int*   sub_ids = (const int*)d_in[3];
    float*       out     = (float*)d_out;
    float*       g       = (float*)d_ws;            // 3 MiB
    const size_t gbytes  = (size_t)B * 3 * T * V * sizeof(float);

    if (ws_size >= gbytes + 64 * sizeof(int)) {
        int* flags = (int*)((char*)d_ws + gbytes);
        hipMemsetAsync(flags, 0, 64 * sizeof(int), stream);
        fused_kernel<<<B * NB, 256, 0, stream>>>(as, del_ids, ins_ids, sub_ids,
                                                 g, flags, out);
    } else {
        gather_kernel<<<B * T, 192, 0, stream>>>(as, del_ids, ins_ids, sub_ids, g);
        dp_kernel<<<B, 256, 0, stream>>>(g, out);
    }
}